// Round 11
// baseline (782.889 us; speedup 1.0000x reference)
//
#include <hip/hip_runtime.h>

#define T_HORIZON 50
#define NU 4
#define NY 4
#define KH 32
#define BPB 64                    // batch elements per block (each wave: all 64)

typedef float v2f __attribute__((ext_vector_type(2)));

// Tied packed FMA: a = w*x + a (dst IS src2). Verified correct in r10.
#define PK_FMA_ACC(a, w, x) \
    asm("v_pk_fma_f32 %0, %1, %2, %0" : "+v"(a) : "s"(w), "v"(x))
// Tied packed MUL: a = w*a. Single instruction, dst tied to src1 slot.
#define PK_MUL_TIED(a, w) \
    asm("v_pk_mul_f32 %0, %1, %0" : "+v"(a) : "s"(w))

#define TANH_SCALE 2.88539008177792681472f

// Stage transposed weights into d_ws: ws[jg][i][k] = W_all[i][jg + 4k]
// i=0..7: Wh rows; i=8: bh; i=9: wor. 4*10*8 = 320 floats.
__global__ void stage_weights(const float* __restrict__ Whg,
                              const float* __restrict__ bhg,
                              const float* __restrict__ Wog,
                              float* __restrict__ ws) {
    int idx = threadIdx.x;
    if (idx < 320) {
        int jg = idx / 80, r = idx % 80, i = r / 8, k = r % 8;
        int j = jg + 4 * k;
        float v = (i < 8) ? Whg[i * KH + j] : (i == 8 ? bhg[j] : Wog[j]);
        ws[idx] = v;
    }
}

__global__ __launch_bounds__(256, 8) void rollout_kernel(
    const float* __restrict__ u,    // (B, 50, 4)
    const float* __restrict__ y0g,  // (B, 4)
    const float* __restrict__ bog,  // (1)
    const float* __restrict__ wsW,  // (4, 10, 8) staged
    float* __restrict__ out)        // (B, 50, 1)
{
    __shared__ __align__(16) float sOut[BPB * T_HORIZON];  // [b_local][t]
    __shared__ float sRed[2][4][BPB];                      // dbuf class partials

    const int tid  = threadIdx.x;
    const int lane = tid & 63;
    const int jg = __builtin_amdgcn_readfirstlane(tid >> 6);

    const float* wb = wsW + jg * 80;   // uniform base
    // Wave-uniform weight pairs -> SGPR pairs (src0 of tied pk ops).
    v2f wh2[8][4], bh2[4];
#pragma unroll
    for (int i = 0; i < 8; ++i)
#pragma unroll
        for (int p = 0; p < 4; ++p)
            wh2[i][p] = *(const v2f*)(wb + i * 8 + 2 * p);
#pragma unroll
    for (int p = 0; p < 4; ++p)
        bh2[p] = *(const v2f*)(wb + 8 * 8 + 2 * p);
    // wor as wave-uniform scalars (SGPR; scalar v_mul takes 1 SGPR src).
    float wor_s[8];
#pragma unroll
    for (int k = 0; k < 8; ++k) wor_s[k] = wb[9 * 8 + k];
    const float bor = bog[0];          // uniform -> SGPR

    const v2f scale2 = {TANH_SCALE, TANH_SCALE};

    const int b = blockIdx.x * BPB + lane;
    const float4* ub = (const float4*)(u + (size_t)b * T_HORIZON * NU);
    float4 yv = *(const float4*)(y0g + (size_t)b * NY);
    // y-state as broadcast pairs (both halves equal) — VGPR operands of pk_fma.
    v2f py1 = {yv.x, yv.x}, py2 = {yv.y, yv.y}, py3 = {yv.z, yv.z}, py4 = {yv.w, yv.w};

    float4 un = ub[0];

    auto step = [&](int t, int buf) {
        float4 uc = un;
        if (t + 1 < T_HORIZON) un = ub[t + 1];

        v2f ux = {uc.x, uc.x}, uy = {uc.y, uc.y}, uz = {uc.z, uc.z}, uw = {uc.w, uc.w};

        float pcls = 0.0f;
#pragma unroll
        for (int p = 0; p < 4; ++p) {
            // identical element order to rounds 2/4/7/8/10: bh, u0..u3, y1..y4
            v2f a = bh2[p];              // SGPR pair -> 2 v_mov into VGPR pair
            PK_FMA_ACC(a, wh2[0][p], ux);
            PK_FMA_ACC(a, wh2[1][p], uy);
            PK_FMA_ACC(a, wh2[2][p], uz);
            PK_FMA_ACC(a, wh2[3][p], uw);
            PK_FMA_ACC(a, wh2[4][p], py1);
            PK_FMA_ACC(a, wh2[5][p], py2);
            PK_FMA_ACC(a, wh2[6][p], py3);
            PK_FMA_ACC(a, wh2[7][p], py4);
            PK_MUL_TIED(a, scale2);      // a := a * scale (packed, tied)

            // tanh tail, minimal scalar ops, inline constants only;
            // per-element identical to all passing rounds:
            // e = exp2(s); r = rcp(e+1); th = fma(-2,r,1); m = th*wor; pcls += m
            float e0 = __builtin_amdgcn_exp2f(a.x);
            float e1 = __builtin_amdgcn_exp2f(a.y);
            float r0 = __builtin_amdgcn_rcpf(e0 + 1.0f);
            float r1 = __builtin_amdgcn_rcpf(e1 + 1.0f);
            float th0 = fmaf(-2.0f, r0, 1.0f);
            float th1 = fmaf(-2.0f, r1, 1.0f);
            float m0 = th0 * wor_s[2 * p];      // k=2p   (j = jg+8p)
            float m1 = th1 * wor_s[2 * p + 1];  // k=2p+1 (j = jg+8p+4)
            pcls += m0;
            pcls += m1;
        }

        // Cross-wave class reduce: double-buffered, ONE barrier per step.
        sRed[buf][jg][lane] = pcls;
        __syncthreads();
        float c0 = sRed[buf][0][lane];
        float c1 = sRed[buf][1][lane];
        float c2 = sRed[buf][2][lane];
        float c3 = sRed[buf][3][lane];
        float partial = (c0 + c1) + (c2 + c3);
        float pred = bor + partial;

        if (jg == 0) sOut[lane * T_HORIZON + t] = pred;

        py4 = py3; py3 = py2; py2 = py1;   // renamed by the x2 unroll, no movs
        py1 = v2f{pred, pred};
    };

    for (int t = 0; t < T_HORIZON; t += 2) {   // T=50 even
        step(t, 0);
        step(t + 1, 1);
    }
    __syncthreads();

    // Coalesced flush: block's out region is contiguous 64*50 floats.
    const float4* s4 = (const float4*)sOut;
    float4* o4 = (float4*)(out + (size_t)blockIdx.x * BPB * T_HORIZON);
#pragma unroll
    for (int k = 0; k < 4; ++k) {
        int idx = k * 256 + tid;
        if (idx < (BPB * T_HORIZON) / 4) o4[idx] = s4[idx];
    }
}

extern "C" void kernel_launch(void* const* d_in, const int* in_sizes, int n_in,
                              void* d_out, int out_size, void* d_ws, size_t ws_size,
                              hipStream_t stream) {
    const float* u   = (const float*)d_in[0];
    const float* y0g = (const float*)d_in[1];
    const float* Whg = (const float*)d_in[2];
    const float* bhg = (const float*)d_in[3];
    const float* Wog = (const float*)d_in[4];
    const float* bog = (const float*)d_in[5];
    float* out = (float*)d_out;
    float* ws  = (float*)d_ws;    // 320 floats staged weights

    stage_weights<<<1, 320, 0, stream>>>(Whg, bhg, Wog, ws);

    const int B = in_sizes[1] / NY;          // 524288
    dim3 grid(B / BPB), block(256);
    rollout_kernel<<<grid, block, 0, stream>>>(u, y0g, bog, ws, out);
}

// Round 12
// 343.819 us; speedup vs baseline: 2.2770x; 2.2770x over previous
//
#include <hip/hip_runtime.h>

#define T_HORIZON 50
#define NU 4
#define NY 4
#define KH 32
#define BPB 64                    // batch elements per block (each wave: all 64)

typedef float v2f __attribute__((ext_vector_type(2)));

// Non-tied packed FMA: d = w*x + c, all VGPR pairs. Single instruction reads
// all sources before writing -> plain "=v" is safe (no early-clobber needed).
#define PK_FMA_NEW(d, w, x, c) \
    asm("v_pk_fma_f32 %0, %1, %2, %3" : "=v"(d) : "v"(w), "v"(x), "v"(c))
// Tied packed FMA: a = w*x + a (dst IS src2). Verified correct in r10.
#define PK_FMA_ACC(a, w, x) \
    asm("v_pk_fma_f32 %0, %1, %2, %0" : "+v"(a) : "v"(w), "v"(x))
// Tied packed MUL: a = s*a.
#define PK_MUL_TIED(a, s) \
    asm("v_pk_mul_f32 %0, %1, %0" : "+v"(a) : "v"(s))

#define TANH_SCALE 2.88539008177792681472f

// Stage transposed weights into d_ws: ws[jg][i][k] = W_all[i][jg + 4k]
// i=0..7: Wh rows; i=8: bh; i=9: wor. 4*10*8 = 320 floats.
__global__ void stage_weights(const float* __restrict__ Whg,
                              const float* __restrict__ bhg,
                              const float* __restrict__ Wog,
                              float* __restrict__ ws) {
    int idx = threadIdx.x;
    if (idx < 320) {
        int jg = idx / 80, r = idx % 80, i = r / 8, k = r % 8;
        int j = jg + 4 * k;
        float v = (i < 8) ? Whg[i * KH + j] : (i == 8 ? bhg[j] : Wog[j]);
        ws[idx] = v;
    }
}

__global__ __launch_bounds__(256, 4) void rollout_kernel(
    const float* __restrict__ u,    // (B, 50, 4)
    const float* __restrict__ y0g,  // (B, 4)
    const float* __restrict__ bog,  // (1)
    const float* __restrict__ wsW,  // (4, 10, 8) staged
    float* __restrict__ out)        // (B, 50, 1)
{
    __shared__ __align__(16) float sOut[BPB * T_HORIZON];  // [b_local][t]
    __shared__ float sRed[2][4][BPB];                      // dbuf class partials

    const int tid  = threadIdx.x;
    const int lane = tid & 63;
    const int jg = __builtin_amdgcn_readfirstlane(tid >> 6);

    const float* wb = wsW + jg * 80;   // uniform base

    // All weight PAIRS live in pinned VGPR pairs: pure-"v" pk ops, no SGPR
    // constraint, no scalarization, no remat possible (asm-defined values).
    v2f wh2[8][4], bh2[4];
#pragma unroll
    for (int i = 0; i < 8; ++i)
#pragma unroll
        for (int p = 0; p < 4; ++p)
            wh2[i][p] = *(const v2f*)(wb + i * 8 + 2 * p);
#pragma unroll
    for (int p = 0; p < 4; ++p)
        bh2[p] = *(const v2f*)(wb + 8 * 8 + 2 * p);
    v2f scale2 = {TANH_SCALE, TANH_SCALE};
#pragma unroll
    for (int i = 0; i < 8; ++i)
#pragma unroll
        for (int p = 0; p < 4; ++p)
            asm volatile("" : "+v"(wh2[i][p]));
#pragma unroll
    for (int p = 0; p < 4; ++p)
        asm volatile("" : "+v"(bh2[p]));
    asm volatile("" : "+v"(scale2));

    // wor/bor as wave-uniform SGPR scalars (scalar v_mul: 1 SGPR src, legal).
    float wor_s[8];
#pragma unroll
    for (int k = 0; k < 8; ++k) wor_s[k] = wb[9 * 8 + k];
    const float bor = bog[0];

    const int b = blockIdx.x * BPB + lane;
    const float4* ub = (const float4*)(u + (size_t)b * T_HORIZON * NU);
    float4 yv = *(const float4*)(y0g + (size_t)b * NY);
    // y-state as broadcast pairs (both halves equal) — VGPR operands of pk_fma.
    v2f py1 = {yv.x, yv.x}, py2 = {yv.y, yv.y}, py3 = {yv.z, yv.z}, py4 = {yv.w, yv.w};

    float4 un = ub[0];

    auto step = [&](int t, int buf) {
        float4 uc = un;
        if (t + 1 < T_HORIZON) un = ub[t + 1];

        v2f ux = {uc.x, uc.x}, uy = {uc.y, uc.y}, uz = {uc.z, uc.z}, uw = {uc.w, uc.w};

        float pcls = 0.0f;
#pragma unroll
        for (int p = 0; p < 4; ++p) {
            // identical element order to rounds 2/4/7/8/10/11: bh, u0..u3, y1..y4
            v2f a;
            PK_FMA_NEW(a, wh2[0][p], ux, bh2[p]);
            PK_FMA_ACC(a, wh2[1][p], uy);
            PK_FMA_ACC(a, wh2[2][p], uz);
            PK_FMA_ACC(a, wh2[3][p], uw);
            PK_FMA_ACC(a, wh2[4][p], py1);
            PK_FMA_ACC(a, wh2[5][p], py2);
            PK_FMA_ACC(a, wh2[6][p], py3);
            PK_FMA_ACC(a, wh2[7][p], py4);
            PK_MUL_TIED(a, scale2);      // a := a * scale (packed, tied)

            // tanh tail, minimal scalar ops, inline constants only;
            // per-element identical to all passing rounds.
            float e0 = __builtin_amdgcn_exp2f(a.x);
            float e1 = __builtin_amdgcn_exp2f(a.y);
            float r0 = __builtin_amdgcn_rcpf(e0 + 1.0f);
            float r1 = __builtin_amdgcn_rcpf(e1 + 1.0f);
            float th0 = fmaf(-2.0f, r0, 1.0f);
            float th1 = fmaf(-2.0f, r1, 1.0f);
            float m0 = th0 * wor_s[2 * p];      // k=2p   (j = jg+8p)
            float m1 = th1 * wor_s[2 * p + 1];  // k=2p+1 (j = jg+8p+4)
            pcls += m0;
            pcls += m1;
        }

        // Cross-wave class reduce: double-buffered, ONE barrier per step.
        sRed[buf][jg][lane] = pcls;
        __syncthreads();
        float c0 = sRed[buf][0][lane];
        float c1 = sRed[buf][1][lane];
        float c2 = sRed[buf][2][lane];
        float c3 = sRed[buf][3][lane];
        float partial = (c0 + c1) + (c2 + c3);
        float pred = bor + partial;

        if (jg == 0) sOut[lane * T_HORIZON + t] = pred;

        py4 = py3; py3 = py2; py2 = py1;   // renamed by the x2 unroll, no movs
        py1 = v2f{pred, pred};
    };

    for (int t = 0; t < T_HORIZON; t += 2) {   // T=50 even
        step(t, 0);
        step(t + 1, 1);
    }
    __syncthreads();

    // Coalesced flush: block's out region is contiguous 64*50 floats.
    const float4* s4 = (const float4*)sOut;
    float4* o4 = (float4*)(out + (size_t)blockIdx.x * BPB * T_HORIZON);
#pragma unroll
    for (int k = 0; k < 4; ++k) {
        int idx = k * 256 + tid;
        if (idx < (BPB * T_HORIZON) / 4) o4[idx] = s4[idx];
    }
}

extern "C" void kernel_launch(void* const* d_in, const int* in_sizes, int n_in,
                              void* d_out, int out_size, void* d_ws, size_t ws_size,
                              hipStream_t stream) {
    const float* u   = (const float*)d_in[0];
    const float* y0g = (const float*)d_in[1];
    const float* Whg = (const float*)d_in[2];
    const float* bhg = (const float*)d_in[3];
    const float* Wog = (const float*)d_in[4];
    const float* bog = (const float*)d_in[5];
    float* out = (float*)d_out;
    float* ws  = (float*)d_ws;    // 320 floats staged weights

    stage_weights<<<1, 320, 0, stream>>>(Whg, bhg, Wog, ws);

    const int B = in_sizes[1] / NY;          // 524288
    dim3 grid(B / BPB), block(256);
    rollout_kernel<<<grid, block, 0, stream>>>(u, y0g, bog, ws, out);
}